// Round 1
// baseline (1656.429 us; speedup 1.0000x reference)
//
#include <hip/hip_runtime.h>

#define B_    2
#define S_    2048
#define D_    1024
#define H_    16
#define DH_   64
#define SCALE_ 0.125f
#define BS_   (B_ * S_)          // 4096 rows for projections
#define HEADEL_ ((size_t)B_ * H_ * S_ * DH_)  // 4,194,304

// ---------------------------------------------------------------------------
// Projection GEMM: Y = X @ W^T + bias
//   X: [M=4096, K=1024] row-major, W: [N=1024, K=1024] row-major
//   head_layout=1 -> write Y[((b*H+h)*S + s)*Dh + d]   (split heads)
//   head_layout=0 -> write Y[m*D + n]                   (flat)
// 64x64 tile, BK=16, 256 threads, 4x4 micro-tile.
// ---------------------------------------------------------------------------
__global__ __launch_bounds__(256)
void proj_kernel(const float* __restrict__ X, const float* __restrict__ W,
                 const float* __restrict__ bias, float* __restrict__ Y,
                 int head_layout)
{
    __shared__ float Xs[16][64];   // [k][m]
    __shared__ float Ws[16][64];   // [k][n]
    const int t    = threadIdx.x;
    const int row0 = blockIdx.x * 64;
    const int col0 = blockIdx.y * 64;
    const int tx = t & 15;         // n micro index
    const int ty = t >> 4;         // m micro index
    const int lm = t >> 2;         // 0..63 : tile row loaded by this thread
    const int lk = (t & 3) * 4;    // 0,4,8,12 : k offset loaded (float4)

    float acc[4][4] = {};

    for (int k0 = 0; k0 < D_; k0 += 16) {
        float4 xa = *(const float4*)&X[(size_t)(row0 + lm) * D_ + k0 + lk];
        float4 wa = *(const float4*)&W[(size_t)(col0 + lm) * D_ + k0 + lk];
        __syncthreads();           // previous iteration's reads done
        Xs[lk + 0][lm] = xa.x; Xs[lk + 1][lm] = xa.y;
        Xs[lk + 2][lm] = xa.z; Xs[lk + 3][lm] = xa.w;
        Ws[lk + 0][lm] = wa.x; Ws[lk + 1][lm] = wa.y;
        Ws[lk + 2][lm] = wa.z; Ws[lk + 3][lm] = wa.w;
        __syncthreads();
        #pragma unroll
        for (int k = 0; k < 16; ++k) {
            float4 a4 = *(const float4*)&Xs[k][ty * 4];
            float4 b4 = *(const float4*)&Ws[k][tx * 4];
            const float a[4] = {a4.x, a4.y, a4.z, a4.w};
            const float b[4] = {b4.x, b4.y, b4.z, b4.w};
            #pragma unroll
            for (int i = 0; i < 4; ++i)
                #pragma unroll
                for (int j = 0; j < 4; ++j)
                    acc[i][j] += a[i] * b[j];
        }
    }

    #pragma unroll
    for (int i = 0; i < 4; ++i) {
        const int m = row0 + ty * 4 + i;
        #pragma unroll
        for (int j = 0; j < 4; ++j) {
            const int n = col0 + tx * 4 + j;
            const float v = acc[i][j] + bias[n];
            if (head_layout) {
                const int bb = m / S_, ss = m % S_;
                const int hh = n / DH_, dd = n % DH_;
                Y[(((size_t)bb * H_ + hh) * S_ + ss) * DH_ + dd] = v;
            } else {
                Y[(size_t)m * D_ + n] = v;
            }
        }
    }
}

// ---------------------------------------------------------------------------
// Scores: attn_raw[bh, q, k] = SCALE * sum_d Q[bh,q,d] * K[bh,k,d]
// One block -> 64x64 score tile, inner K = 64 single pass.
// Tiles stored transposed in LDS so the d-loop reads are ds_read_b128.
// ---------------------------------------------------------------------------
__global__ __launch_bounds__(256)
void scores_kernel(const float* __restrict__ Qh, const float* __restrict__ Kh,
                   float* __restrict__ attn)
{
    __shared__ float Qt[64][68];   // [d][m]  (+4 pad keeps 16B alignment)
    __shared__ float Kt[64][68];   // [d][n]
    const int t  = threadIdx.x;
    const int q0 = blockIdx.x * 64;
    const int k0 = blockIdx.y * 64;
    const int bh = blockIdx.z;
    const float* Qb = Qh + (size_t)bh * S_ * DH_;
    const float* Kb = Kh + (size_t)bh * S_ * DH_;

    const int lr = t >> 2;          // 0..63 tile row
    const int lc = (t & 3) * 16;    // 0,16,32,48
    #pragma unroll
    for (int j = 0; j < 16; j += 4) {
        float4 a = *(const float4*)&Qb[(size_t)(q0 + lr) * DH_ + lc + j];
        float4 b = *(const float4*)&Kb[(size_t)(k0 + lr) * DH_ + lc + j];
        Qt[lc + j + 0][lr] = a.x; Qt[lc + j + 1][lr] = a.y;
        Qt[lc + j + 2][lr] = a.z; Qt[lc + j + 3][lr] = a.w;
        Kt[lc + j + 0][lr] = b.x; Kt[lc + j + 1][lr] = b.y;
        Kt[lc + j + 2][lr] = b.z; Kt[lc + j + 3][lr] = b.w;
    }
    __syncthreads();

    const int tx = t & 15, ty = t >> 4;
    float acc[4][4] = {};
    #pragma unroll 4
    for (int d = 0; d < 64; ++d) {
        float4 a4 = *(const float4*)&Qt[d][ty * 4];
        float4 b4 = *(const float4*)&Kt[d][tx * 4];
        const float a[4] = {a4.x, a4.y, a4.z, a4.w};
        const float b[4] = {b4.x, b4.y, b4.z, b4.w};
        #pragma unroll
        for (int i = 0; i < 4; ++i)
            #pragma unroll
            for (int j = 0; j < 4; ++j)
                acc[i][j] += a[i] * b[j];
    }

    #pragma unroll
    for (int i = 0; i < 4; ++i) {
        const size_t row = (size_t)bh * S_ + q0 + ty * 4 + i;
        float4 o;
        o.x = acc[i][0] * SCALE_; o.y = acc[i][1] * SCALE_;
        o.z = acc[i][2] * SCALE_; o.w = acc[i][3] * SCALE_;
        *(float4*)&attn[row * S_ + k0 + tx * 4] = o;
    }
}

// ---------------------------------------------------------------------------
// Softmax in place over rows of length 2048. One 256-thread block per row.
// ---------------------------------------------------------------------------
__global__ __launch_bounds__(256)
void softmax_kernel(float* __restrict__ attn)
{
    float* p = attn + (size_t)blockIdx.x * S_;
    const int t = threadIdx.x;
    float x[8];
    *(float4*)&x[0] = *(const float4*)&p[t * 4];
    *(float4*)&x[4] = *(const float4*)&p[1024 + t * 4];

    float m = x[0];
    #pragma unroll
    for (int u = 1; u < 8; ++u) m = fmaxf(m, x[u]);
    #pragma unroll
    for (int off = 32; off >= 1; off >>= 1) m = fmaxf(m, __shfl_xor(m, off));

    __shared__ float redm[4];
    __shared__ float reds[4];
    if ((t & 63) == 0) redm[t >> 6] = m;
    __syncthreads();
    m = fmaxf(fmaxf(redm[0], redm[1]), fmaxf(redm[2], redm[3]));

    float s = 0.f;
    #pragma unroll
    for (int u = 0; u < 8; ++u) { x[u] = __expf(x[u] - m); s += x[u]; }
    #pragma unroll
    for (int off = 32; off >= 1; off >>= 1) s += __shfl_xor(s, off);
    if ((t & 63) == 0) reds[t >> 6] = s;
    __syncthreads();
    s = (reds[0] + reds[1]) + (reds[2] + reds[3]);

    const float inv = 1.0f / s;
    #pragma unroll
    for (int u = 0; u < 8; ++u) x[u] *= inv;
    *(float4*)&p[t * 4]        = *(const float4*)&x[0];
    *(float4*)&p[1024 + t * 4] = *(const float4*)&x[4];
}

// ---------------------------------------------------------------------------
// PV: OH[b, q, h*Dh + d] = sum_j attn[bh, q, j] * V[bh, j, d]
// One block -> 64 q-rows x 64 d-cols for one (b,h). K-loop over S in 16-chunks.
// ---------------------------------------------------------------------------
__global__ __launch_bounds__(256)
void pv_kernel(const float* __restrict__ attn, const float* __restrict__ Vh,
               float* __restrict__ OH)
{
    __shared__ float At[16][68];   // [k][m]
    __shared__ float Vt[16][64];   // [k][d]
    const int t  = threadIdx.x;
    const int q0 = blockIdx.x * 64;
    const int bh = blockIdx.y;
    const float* Ab = attn + (size_t)bh * S_ * S_;
    const float* Vb = Vh   + (size_t)bh * S_ * DH_;

    const int lm = t >> 2;         // 0..63
    const int lk = (t & 3) * 4;    // 0,4,8,12
    const int vr = t >> 4;         // 0..15  V tile row
    const int vc = (t & 15) * 4;   // V tile col
    const int tx = t & 15, ty = t >> 4;

    float acc[4][4] = {};

    for (int j0 = 0; j0 < S_; j0 += 16) {
        float4 a = *(const float4*)&Ab[(size_t)(q0 + lm) * S_ + j0 + lk];
        float4 v = *(const float4*)&Vb[(size_t)(j0 + vr) * DH_ + vc];
        __syncthreads();
        At[lk + 0][lm] = a.x; At[lk + 1][lm] = a.y;
        At[lk + 2][lm] = a.z; At[lk + 3][lm] = a.w;
        *(float4*)&Vt[vr][vc] = v;
        __syncthreads();
        #pragma unroll
        for (int k = 0; k < 16; ++k) {
            float4 a4 = *(const float4*)&At[k][ty * 4];
            float4 b4 = *(const float4*)&Vt[k][tx * 4];
            const float aa[4] = {a4.x, a4.y, a4.z, a4.w};
            const float bb[4] = {b4.x, b4.y, b4.z, b4.w};
            #pragma unroll
            for (int i = 0; i < 4; ++i)
                #pragma unroll
                for (int j = 0; j < 4; ++j)
                    acc[i][j] += aa[i] * bb[j];
        }
    }

    const int b = bh >> 4;         // bh / H
    const int h = bh & 15;         // bh % H
    #pragma unroll
    for (int i = 0; i < 4; ++i) {
        float4 o;
        o.x = acc[i][0]; o.y = acc[i][1]; o.z = acc[i][2]; o.w = acc[i][3];
        *(float4*)&OH[((size_t)b * S_ + q0 + ty * 4 + i) * D_ + h * DH_ + tx * 4] = o;
    }
}

// ---------------------------------------------------------------------------
extern "C" void kernel_launch(void* const* d_in, const int* in_sizes, int n_in,
                              void* d_out, int out_size, void* d_ws, size_t ws_size,
                              hipStream_t stream)
{
    const float* q  = (const float*)d_in[0];
    const float* k  = (const float*)d_in[1];
    const float* v  = (const float*)d_in[2];
    const float* Wq = (const float*)d_in[3];
    const float* bq = (const float*)d_in[4];
    const float* Wk = (const float*)d_in[5];
    const float* bk = (const float*)d_in[6];
    const float* Wv = (const float*)d_in[7];
    const float* bv = (const float*)d_in[8];
    const float* Wo = (const float*)d_in[9];
    const float* bo = (const float*)d_in[10];

    float* out  = (float*)d_out;                       // [B,S,D]
    float* attn = out + (size_t)B_ * S_ * D_;          // [B,H,S,S]

    float* ws = (float*)d_ws;
    float* qs = ws;                  // [B,H,S,Dh]
    float* ks = qs + HEADEL_;
    float* vs = ks + HEADEL_;
    float* oh = vs + HEADEL_;        // [B,S,D] gathered PV output

    const dim3 gproj(BS_ / 64, D_ / 64);   // 64 x 16
    proj_kernel<<<gproj, 256, 0, stream>>>(q, Wq, bq, qs, 1);
    proj_kernel<<<gproj, 256, 0, stream>>>(k, Wk, bk, ks, 1);
    proj_kernel<<<gproj, 256, 0, stream>>>(v, Wv, bv, vs, 1);

    scores_kernel<<<dim3(S_ / 64, S_ / 64, B_ * H_), 256, 0, stream>>>(qs, ks, attn);
    softmax_kernel<<<B_ * H_ * S_, 256, 0, stream>>>(attn);
    pv_kernel<<<dim3(S_ / 64, B_ * H_), 256, 0, stream>>>(attn, vs, oh);

    proj_kernel<<<gproj, 256, 0, stream>>>(oh, Wo, bo, out, 0);
}